// Round 20
// baseline (60.827 us; speedup 1.0000x reference)
//
#include <hip/hip_runtime.h>
#include <hip/hip_bf16.h>
#include <math.h>

// logits [8,19,256,512] f32, targets [8,256,512] int32
// R=20 truncated EDT, loss = mean_b sum_c mean_hw probs*sdf
#define NCLS 19
#define BB   8
#define HH   256
#define WW   512
#define CAP2 400u     // R^2; any value >= 400 caps identically
#define SEG  8        // rows per kA segment
#define WPC  70       // uint4 per class row in LDS (280 dwords: halo12+256+halo12)

typedef unsigned short u16x2 __attribute__((ext_vector_type(2)));

static __device__ __forceinline__ unsigned umin32(unsigned a, unsigned b) { return a < b ? a : b; }
static __device__ __forceinline__ float fsqrt_fast(float x) { return __builtin_amdgcn_sqrtf(x); }

static __device__ __forceinline__ unsigned pk_add_s(unsigned v, unsigned c) {
    unsigned d; asm("v_pk_add_u16 %0, %1, %2" : "=v"(d) : "s"(c), "v"(v)); return d;
}
static __device__ __forceinline__ unsigned pk_minv(unsigned a, unsigned b) {
    unsigned d; asm("v_pk_min_u16 %0, %1, %2" : "=v"(d) : "v"(a), "v"(b)); return d;
}
static __device__ __forceinline__ unsigned pk_hmin(unsigned a) {
    unsigned d;
    asm("v_pk_min_u16 %0, %1, %1 op_sel:[1,0] op_sel_hi:[0,1]" : "=v"(d) : "v"(a));
    return d;
}
// 4 u8 distances in x -> two packed-u16 squared words (verified r5)
static __device__ __forceinline__ void sq8(unsigned x, unsigned& w0, unsigned& w1) {
    unsigned a = x & 0x00FF00FFu;
    unsigned b = (x >> 8) & 0x00FF00FFu;
    u16x2 sa = __builtin_bit_cast(u16x2, a); sa = sa * sa;
    u16x2 sb = __builtin_bit_cast(u16x2, b); sb = sb * sb;
    unsigned ua = __builtin_bit_cast(unsigned, sa);
    unsigned ub = __builtin_bit_cast(unsigned, sb);
    w0 = __builtin_amdgcn_perm(ub, ua, 0x05040100u);
    w1 = __builtin_amdgcn_perm(ub, ua, 0x07060302u);
}

// ---------------------------------------------------------------------------
// Kernel A: vertical pass, SEG=8, class-split (10 classes/thread, class 9
// duplicated across halves - benign double-write of identical value).
// 262144 threads = 4 waves/SIMD. Block 0 zeroes the 64 accumulator cells.
// ---------------------------------------------------------------------------
__global__ __launch_bounds__(256)
void kA_vert(const int* __restrict__ targ, unsigned char* __restrict__ vneg,
             unsigned long long* __restrict__ acc) {
    if (blockIdx.x == 0 && threadIdx.x < 64) acc[threadIdx.x] = 0ULL;
    int gid = blockIdx.x * 256 + threadIdx.x;  // 4096 cols * 32 segs * 2 halves
    int col = gid & 4095;                      // lanes adjacent in w -> coalesced
    int seg = (gid >> 12) & 31;
    int c0 = (gid >> 17) * 9;                  // 0 or 9 (classes c0..c0+9)
    int b = col >> 9;
    int w = col & 511;
    int h0 = seg * SEG;
    const int* tp = &targ[b * HH * WW + w];

    unsigned d[10];
    unsigned pk[10][2];   // 8 rows of u8 distances per class
#pragma unroll
    for (int cc = 0; cc < 10; ++cc) { d[cc] = 21u; pk[cc][0] = 0u; pk[cc][1] = 0u; }
#pragma unroll
    for (int k = 0; k < 21 + SEG; ++k) {
        int hh = h0 - 21 + k;
        int t = -1;
        if (hh >= 0) t = tp[hh * WW];          // uniform branch (top segs only)
#pragma unroll
        for (int cc = 0; cc < 10; ++cc)
            d[cc] = (t == c0 + cc) ? 0u : d[cc] + 1u;
        if (k >= 21) {
            int r = k - 21;
#pragma unroll
            for (int cc = 0; cc < 10; ++cc)
                pk[cc][r >> 2] |= d[cc] << ((r & 3) * 8);
        }
    }
    unsigned u[10];
#pragma unroll
    for (int cc = 0; cc < 10; ++cc) u[cc] = 21u;
#pragma unroll
    for (int k = 0; k < 21 + SEG; ++k) {
        int hh = h0 + 21 + SEG - 1 - k;
        int t = -1;
        if (hh < HH) t = tp[hh * WW];          // uniform branch (bottom segs)
#pragma unroll
        for (int cc = 0; cc < 10; ++cc)
            u[cc] = (t == c0 + cc) ? 0u : u[cc] + 1u;
        if (k >= 21) {
            int r = 21 + SEG - 1 - k;          // 7..0
#pragma unroll
            for (int cc = 0; cc < 10; ++cc) {
                unsigned dv = (pk[cc][r >> 2] >> ((r & 3) * 8)) & 0xffu;
                vneg[((size_t)(b * NCLS + c0 + cc) * HH + hh) * WW + w] =
                    (unsigned char)umin32(dv, u[cc]);
            }
        }
    }
}

// ---------------------------------------------------------------------------
// Kernel B: one BLOCK (4 waves) per row; wave w owns classes {w, w+4, ...}.
// r19 body with the CASCADE REMOVED: straight-line 21-tap min-plus, no vote,
// no branch. The cascade saved only ~20% of packed ops net, but its
// s_cmp+branch split each class body into 3 scheduling regions, preventing
// the compiler from issuing all 7 ds_read_b128 back-to-back and pipelining
// the min chains / TRANS epilogue across the waits. Branch-free body = one
// region. Keeps: 2-deep logits prefetch, overlay merge, 64-cell atomic.
// ---------------------------------------------------------------------------
__global__ __launch_bounds__(256)
void kB_main(const float* __restrict__ logits,
             const unsigned char* __restrict__ vneg,
             unsigned long long* __restrict__ acc) {
    __shared__ __align__(16) unsigned smem[NCLS * 280];   // 21280 B, stage+merge
    int tid = threadIdx.x;
    int L = tid & 63;
    int wid = tid >> 6;
    int bh = blockIdx.x;               // row 0..2047
    int b = bh >> 8;
    int h = bh & 255;

    // merge-phase overlay (valid only after the post-compute barrier)
    float (*sNum)[256] = (float (*)[256])smem;                       // [4][256]
    float (*sDen)[256] = (float (*)[256])(smem + 1024);
    float (*sEt)[256]  = (float (*)[256])(smem + 2048);
    unsigned short (*sM2)[256] = (unsigned short (*)[256])(smem + 3072);
    float* wsum = (float*)(smem + 3584);

#define SQx(x) ((unsigned)((x) * (x)))
#define PK2(a, bq) (SQx(a) | (SQx(bq) << 16))
    const unsigned CE[21] = {
        PK2(-20,-19), PK2(-18,-17), PK2(-16,-15), PK2(-14,-13), PK2(-12,-11),
        PK2(-10,-9),  PK2(-8,-7),   PK2(-6,-5),   PK2(-4,-3),   PK2(-2,-1),
        PK2(0,1),     PK2(2,3),     PK2(4,5),     PK2(6,7),     PK2(8,9),
        PK2(10,11),   PK2(12,13),   PK2(14,15),   PK2(16,17),   PK2(18,19),
        PK2(20,21) };
    const unsigned CO[21] = {
        PK2(-21,-20), PK2(-19,-18), PK2(-17,-16), PK2(-15,-14), PK2(-13,-12),
        PK2(-11,-10), PK2(-9,-8),   PK2(-7,-6),   PK2(-5,-4),   PK2(-3,-2),
        PK2(-1,0),    PK2(1,2),     PK2(3,4),     PK2(5,6),     PK2(7,8),
        PK2(9,10),    PK2(11,12),   PK2(13,14),   PK2(15,16),   PK2(17,18),
        PK2(19,20) };
#undef PK2
#undef SQx

    const unsigned HALO2 = 441u | (441u << 16);
    const float* lroww = &logits[((size_t)(b * NCLS + wid) * HH + h) * WW + 8 * L];
    int nc = (wid < 3) ? 5 : 4;

    // ---- wave-local stage, batched loads ----
    uint2 v8s[5];
#pragma unroll
    for (int i = 0; i < 5; ++i)
        if (i < nc)
            v8s[i] = ((const uint2*)vneg)
                [((size_t)(b * NCLS + wid + 4 * i) * HH + h) * 64 + L];
#pragma unroll
    for (int i = 0; i < 5; ++i)
        if (i < nc) {
            int c = wid + 4 * i;
            uint4 wq;
            sq8(v8s[i].x, wq.x, wq.y);
            sq8(v8s[i].y, wq.z, wq.w);
            ((uint4*)smem)[c * WPC + L + 3] = wq;          // dwords k=4L+12..15
            if (L < 12) smem[c * 280 + L] = HALO2;         // k=0..11
            if (L >= 52) smem[c * 280 + 216 + L] = HALO2;  // k=268..279
        }

    float den[8], num[8], et[8];
    unsigned m2[8];
#pragma unroll
    for (int p = 0; p < 8; ++p) { den[p]=0.f; num[p]=0.f; et[p]=0.f; m2[p]=0xFFFFu; }

    // 2-deep logits prefetch pipeline
    float4 f0n = *(const float4*)lroww;                    // class i=0
    float4 f1n = *(const float4*)(lroww + 4);
    const float* l1 = lroww + (size_t)4 * (HH * WW);       // class i=1 (nc>=4)
    float4 f0n2 = *(const float4*)l1;
    float4 f1n2 = *(const float4*)(l1 + 4);

#pragma unroll 1
    for (int i = 0; i < nc; ++i) {
        int c = wid + 4 * i;
        float4 f0 = f0n, f1 = f1n;
        f0n = f0n2; f1n = f1n2;
        if (i + 2 < nc) {   // issue class i+2's loads now (2 bodies ahead)
            const float* ln = lroww + (size_t)(i + 2) * 4 * (HH * WW);
            f0n2 = *(const float4*)ln;
            f1n2 = *(const float4*)(ln + 4);
        }

        // full window: 7 ds_read_b128 issued back-to-back (branch-free body)
        const uint4* basep = (const uint4*)smem + c * WPC + L;
        uint4 q0 = basep[0], q1 = basep[1], q2 = basep[2], q3 = basep[3],
              q4 = basep[4], q5 = basep[5], q6 = basep[6];
        unsigned W[28] = {q0.x,q0.y,q0.z,q0.w, q1.x,q1.y,q1.z,q1.w,
                          q2.x,q2.y,q2.z,q2.w, q3.x,q3.y,q3.z,q3.w,
                          q4.x,q4.y,q4.z,q4.w, q5.x,q5.y,q5.z,q5.w,
                          q6.x,q6.y,q6.z,q6.w};

        unsigned ae[4], ao[4];
#pragma unroll
        for (int r = 0; r < 4; ++r) { ae[r] = 0xFFFFFFFFu; ao[r] = 0xFFFFFFFFu; }
#pragma unroll
        for (int r = 0; r < 4; ++r)
#pragma unroll
            for (int m = 0; m <= 20; ++m) {
                ae[r] = pk_minv(ae[r], pk_add_s(W[r + m + 2], CE[m]));
                ao[r] = pk_minv(ao[r], pk_add_s(W[r + m + 2], CO[m]));
            }

        float fx[8] = {f0.x, f0.y, f0.z, f0.w, f1.x, f1.y, f1.z, f1.w};
#pragma unroll
        for (int r = 0; r < 4; ++r) {
            unsigned nd0 = pk_hmin(ae[r]) & 0xFFFFu;   // px 8L+2r
            unsigned nd1 = pk_hmin(ao[r]) & 0xFFFFu;   // px 8L+2r+1
            float e0 = __expf(fx[2 * r]), e1 = __expf(fx[2 * r + 1]);
            den[2 * r] += e0; den[2 * r + 1] += e1;
            float s0 = fsqrt_fast((float)umin32(nd0, CAP2));
            float s1 = fsqrt_fast((float)umin32(nd1, CAP2));
            num[2 * r]     += e0 * s0;     // target term: e*sqrt(0)=0, self-excluded
            num[2 * r + 1] += e1 * s1;
            bool z0 = (nd0 == 0), z1 = (nd1 == 0);
            et[2 * r]     = z0 ? e0 : et[2 * r];
            et[2 * r + 1] = z1 ? e1 : et[2 * r + 1];
            m2[2 * r]     = umin32(m2[2 * r],     z0 ? 0xFFFFu : nd0);
            m2[2 * r + 1] = umin32(m2[2 * r + 1], z1 ? 0xFFFFu : nd1);
        }
    }

    // ---- two-pass merge, OVERLAID on the stage buffer ----
    __syncthreads();   // all waves done reading stage LDS; safe to overwrite
    float vsum = 0.f;
#pragma unroll
    for (int pass = 0; pass < 2; ++pass) {
        if ((L >> 5) == pass) {                 // lanes owning this half-row
            int base = 8 * (L & 31);
            *(float4*)&sNum[wid][base]     = (float4){num[0], num[1], num[2], num[3]};
            *(float4*)&sNum[wid][base + 4] = (float4){num[4], num[5], num[6], num[7]};
            *(float4*)&sDen[wid][base]     = (float4){den[0], den[1], den[2], den[3]};
            *(float4*)&sDen[wid][base + 4] = (float4){den[4], den[5], den[6], den[7]};
            *(float4*)&sEt[wid][base]      = (float4){et[0], et[1], et[2], et[3]};
            *(float4*)&sEt[wid][base + 4]  = (float4){et[4], et[5], et[6], et[7]};
            uint4 mq;
            mq.x = m2[0] | (m2[1] << 16); mq.y = m2[2] | (m2[3] << 16);
            mq.z = m2[4] | (m2[5] << 16); mq.w = m2[6] | (m2[7] << 16);
            *(uint4*)&sM2[wid][base] = mq;
        }
        __syncthreads();
        {
            float N = sNum[0][tid] + sNum[1][tid] + sNum[2][tid] + sNum[3][tid];
            float D = sDen[0][tid] + sDen[1][tid] + sDen[2][tid] + sDen[3][tid];
            float E = sEt[0][tid] + sEt[1][tid] + sEt[2][tid] + sEt[3][tid];
            unsigned M = umin32(umin32((unsigned)sM2[0][tid], (unsigned)sM2[1][tid]),
                                umin32((unsigned)sM2[2][tid], (unsigned)sM2[3][tid]));
            vsum += (N - E * fsqrt_fast((float)umin32(M, CAP2))) / D;
        }
        __syncthreads();                        // before next pass overwrites
    }

#pragma unroll
    for (int off = 32; off >= 1; off >>= 1) vsum += __shfl_down(vsum, off);
    if (L == 0) wsum[wid] = vsum;
    __syncthreads();
    if (tid == 0) {
        float s = (wsum[0] + wsum[1]) + (wsum[2] + wsum[3]);
        // fixed-point 2^36 with /20 folded in; integer atomic => deterministic
        double q = (double)s * (68719476736.0 / 20.0);
        atomicAdd(&acc[bh & 63], (unsigned long long)(long long)q);
    }
}

// one wave: parallel cell loads + shuffle reduce (integer = deterministic)
__global__ void kC_final(const unsigned long long* __restrict__ acc,
                         float* __restrict__ out) {
    int L = threadIdx.x;
    long long v = (long long)acc[L];
#pragma unroll
    for (int off = 32; off >= 1; off >>= 1) v += __shfl_down(v, off);
    if (L == 0) {
        double d = (double)v / 68719476736.0;
        out[0] = (float)(d / (double)((size_t)BB * HH * WW));
    }
}

extern "C" void kernel_launch(void* const* d_in, const int* in_sizes, int n_in,
                              void* d_out, int out_size, void* d_ws, size_t ws_size,
                              hipStream_t stream) {
    const float* logits = (const float*)d_in[0];
    const int* targ = (const int*)d_in[1];
    unsigned char* wsb = (unsigned char*)d_ws;
    unsigned long long* acc = (unsigned long long*)wsb;       // [0,512): 64 cells
    unsigned char* vneg = wsb + 1024;                         // 19.9 MB u8

    kA_vert<<<1024, 256, 0, stream>>>(targ, vneg, acc);       // 262144 threads
    kB_main<<<BB * HH, 256, 0, stream>>>(logits, vneg, acc);
    kC_final<<<1, 64, 0, stream>>>(acc, (float*)d_out);
}

// Round 21
// 54.098 us; speedup vs baseline: 1.1244x; 1.1244x over previous
//
#include <hip/hip_runtime.h>
#include <hip/hip_bf16.h>
#include <math.h>

// logits [8,19,256,512] f32, targets [8,256,512] int32
// R=20 truncated EDT, loss = mean_b sum_c mean_hw probs*sdf
//
// FINAL (r19 config, 54.2us measured): kA class-split vertical scan,
// kB fused horizontal-EDT+softmax+loss w/ cascade vote + 2-deep prefetch,
// kC wave-reduce. Counter-backed design decisions inline.
#define NCLS 19
#define BB   8
#define HH   256
#define WW   512
#define CAP2 400u     // R^2; any value >= 400 caps identically
#define SEG  8        // rows per kA segment
#define WPC  70       // uint4 per class row in LDS (280 dwords: halo12+256+halo12)

typedef unsigned short u16x2 __attribute__((ext_vector_type(2)));

static __device__ __forceinline__ unsigned umin32(unsigned a, unsigned b) { return a < b ? a : b; }
static __device__ __forceinline__ float fsqrt_fast(float x) { return __builtin_amdgcn_sqrtf(x); }

static __device__ __forceinline__ unsigned pk_add_s(unsigned v, unsigned c) {
    unsigned d; asm("v_pk_add_u16 %0, %1, %2" : "=v"(d) : "s"(c), "v"(v)); return d;
}
static __device__ __forceinline__ unsigned pk_minv(unsigned a, unsigned b) {
    unsigned d; asm("v_pk_min_u16 %0, %1, %2" : "=v"(d) : "v"(a), "v"(b)); return d;
}
static __device__ __forceinline__ unsigned pk_maxv(unsigned a, unsigned b) {
    unsigned d; asm("v_pk_max_u16 %0, %1, %2" : "=v"(d) : "v"(a), "v"(b)); return d;
}
static __device__ __forceinline__ unsigned pk_hmin(unsigned a) {
    unsigned d;
    asm("v_pk_min_u16 %0, %1, %1 op_sel:[1,0] op_sel_hi:[0,1]" : "=v"(d) : "v"(a));
    return d;
}
// 4 u8 distances in x -> two packed-u16 squared words (verified r5)
static __device__ __forceinline__ void sq8(unsigned x, unsigned& w0, unsigned& w1) {
    unsigned a = x & 0x00FF00FFu;
    unsigned b = (x >> 8) & 0x00FF00FFu;
    u16x2 sa = __builtin_bit_cast(u16x2, a); sa = sa * sa;
    u16x2 sb = __builtin_bit_cast(u16x2, b); sb = sb * sb;
    unsigned ua = __builtin_bit_cast(unsigned, sa);
    unsigned ub = __builtin_bit_cast(unsigned, sb);
    w0 = __builtin_amdgcn_perm(ub, ua, 0x05040100u);
    w1 = __builtin_amdgcn_perm(ub, ua, 0x07060302u);
}

// ---------------------------------------------------------------------------
// Kernel A: vertical pass, SEG=8, class-split (10 classes/thread, class 9
// duplicated across halves - benign double-write of identical value).
// 262144 threads = 4 waves/SIMD. Block 0 zeroes the 64 accumulator cells.
// ---------------------------------------------------------------------------
__global__ __launch_bounds__(256)
void kA_vert(const int* __restrict__ targ, unsigned char* __restrict__ vneg,
             unsigned long long* __restrict__ acc) {
    if (blockIdx.x == 0 && threadIdx.x < 64) acc[threadIdx.x] = 0ULL;
    int gid = blockIdx.x * 256 + threadIdx.x;  // 4096 cols * 32 segs * 2 halves
    int col = gid & 4095;                      // lanes adjacent in w -> coalesced
    int seg = (gid >> 12) & 31;
    int c0 = (gid >> 17) * 9;                  // 0 or 9 (classes c0..c0+9)
    int b = col >> 9;
    int w = col & 511;
    int h0 = seg * SEG;
    const int* tp = &targ[b * HH * WW + w];

    unsigned d[10];
    unsigned pk[10][2];   // 8 rows of u8 distances per class
#pragma unroll
    for (int cc = 0; cc < 10; ++cc) { d[cc] = 21u; pk[cc][0] = 0u; pk[cc][1] = 0u; }
#pragma unroll
    for (int k = 0; k < 21 + SEG; ++k) {
        int hh = h0 - 21 + k;
        int t = -1;
        if (hh >= 0) t = tp[hh * WW];          // uniform branch (top segs only)
#pragma unroll
        for (int cc = 0; cc < 10; ++cc)
            d[cc] = (t == c0 + cc) ? 0u : d[cc] + 1u;
        if (k >= 21) {
            int r = k - 21;
#pragma unroll
            for (int cc = 0; cc < 10; ++cc)
                pk[cc][r >> 2] |= d[cc] << ((r & 3) * 8);
        }
    }
    unsigned u[10];
#pragma unroll
    for (int cc = 0; cc < 10; ++cc) u[cc] = 21u;
#pragma unroll
    for (int k = 0; k < 21 + SEG; ++k) {
        int hh = h0 + 21 + SEG - 1 - k;
        int t = -1;
        if (hh < HH) t = tp[hh * WW];          // uniform branch (bottom segs)
#pragma unroll
        for (int cc = 0; cc < 10; ++cc)
            u[cc] = (t == c0 + cc) ? 0u : u[cc] + 1u;
        if (k >= 21) {
            int r = 21 + SEG - 1 - k;          // 7..0
#pragma unroll
            for (int cc = 0; cc < 10; ++cc) {
                unsigned dv = (pk[cc][r >> 2] >> ((r & 3) * 8)) & 0xffu;
                vneg[((size_t)(b * NCLS + c0 + cc) * HH + hh) * WW + w] =
                    (unsigned char)umin32(dv, u[cc]);
            }
        }
    }
}

// ---------------------------------------------------------------------------
// Kernel B: one BLOCK (4 waves) per row; wave w owns classes {w, w+4, ...}.
// Cascade vote KEPT (r20 ablation: removing it cost +9us - work-skip beats
// region-unification). 2-deep logits prefetch (r19: -2us). Wave-local LDS
// stage (batched loads), 3+4 deferred ds_read_b128 window, targets-free
// epilogue (nd[target]==0 uniquely), overlay merge, 64-cell scatter atomic.
// No device fences (r7: L2 poison), no min-waves bound (r10: spill storm).
// ---------------------------------------------------------------------------
__global__ __launch_bounds__(256)
void kB_main(const float* __restrict__ logits,
             const unsigned char* __restrict__ vneg,
             unsigned long long* __restrict__ acc) {
    __shared__ __align__(16) unsigned smem[NCLS * 280];   // 21280 B, stage+merge
    int tid = threadIdx.x;
    int L = tid & 63;
    int wid = tid >> 6;
    int bh = blockIdx.x;               // row 0..2047
    int b = bh >> 8;
    int h = bh & 255;

    // merge-phase overlay (valid only after the post-compute barrier)
    float (*sNum)[256] = (float (*)[256])smem;                       // [4][256]
    float (*sDen)[256] = (float (*)[256])(smem + 1024);
    float (*sEt)[256]  = (float (*)[256])(smem + 2048);
    unsigned short (*sM2)[256] = (unsigned short (*)[256])(smem + 3072);
    float* wsum = (float*)(smem + 3584);

#define SQx(x) ((unsigned)((x) * (x)))
#define PK2(a, bq) (SQx(a) | (SQx(bq) << 16))
    const unsigned CE[21] = {
        PK2(-20,-19), PK2(-18,-17), PK2(-16,-15), PK2(-14,-13), PK2(-12,-11),
        PK2(-10,-9),  PK2(-8,-7),   PK2(-6,-5),   PK2(-4,-3),   PK2(-2,-1),
        PK2(0,1),     PK2(2,3),     PK2(4,5),     PK2(6,7),     PK2(8,9),
        PK2(10,11),   PK2(12,13),   PK2(14,15),   PK2(16,17),   PK2(18,19),
        PK2(20,21) };
    const unsigned CO[21] = {
        PK2(-21,-20), PK2(-19,-18), PK2(-17,-16), PK2(-15,-14), PK2(-13,-12),
        PK2(-11,-10), PK2(-9,-8),   PK2(-7,-6),   PK2(-5,-4),   PK2(-3,-2),
        PK2(-1,0),    PK2(1,2),     PK2(3,4),     PK2(5,6),     PK2(7,8),
        PK2(9,10),    PK2(11,12),   PK2(13,14),   PK2(15,16),   PK2(17,18),
        PK2(19,20) };
#undef PK2
#undef SQx

    const unsigned HALO2 = 441u | (441u << 16);
    const float* lroww = &logits[((size_t)(b * NCLS + wid) * HH + h) * WW + 8 * L];
    int nc = (wid < 3) ? 5 : 4;

    // ---- wave-local stage, batched loads ----
    uint2 v8s[5];
#pragma unroll
    for (int i = 0; i < 5; ++i)
        if (i < nc)
            v8s[i] = ((const uint2*)vneg)
                [((size_t)(b * NCLS + wid + 4 * i) * HH + h) * 64 + L];
#pragma unroll
    for (int i = 0; i < 5; ++i)
        if (i < nc) {
            int c = wid + 4 * i;
            uint4 wq;
            sq8(v8s[i].x, wq.x, wq.y);
            sq8(v8s[i].y, wq.z, wq.w);
            ((uint4*)smem)[c * WPC + L + 3] = wq;          // dwords k=4L+12..15
            if (L < 12) smem[c * 280 + L] = HALO2;         // k=0..11
            if (L >= 52) smem[c * 280 + 216 + L] = HALO2;  // k=268..279
        }

    float den[8], num[8], et[8];
    unsigned m2[8];
#pragma unroll
    for (int p = 0; p < 8; ++p) { den[p]=0.f; num[p]=0.f; et[p]=0.f; m2[p]=0xFFFFu; }

    // 2-deep logits prefetch pipeline
    float4 f0n = *(const float4*)lroww;                    // class i=0
    float4 f1n = *(const float4*)(lroww + 4);
    const float* l1 = lroww + (size_t)4 * (HH * WW);       // class i=1 (nc>=4 always)
    float4 f0n2 = *(const float4*)l1;
    float4 f1n2 = *(const float4*)(l1 + 4);

#pragma unroll 1
    for (int i = 0; i < nc; ++i) {
        int c = wid + 4 * i;
        float4 f0 = f0n, f1 = f1n;
        f0n = f0n2; f1n = f1n2;
        {   // issue class i+2's loads now (2 bodies ahead of use)
            int ipre = (i + 2 < nc) ? (i + 2) : i;         // clamped: in-bounds
            const float* ln = lroww + (size_t)ipre * 4 * (HH * WW);
            f0n2 = *(const float4*)ln;
            f1n2 = *(const float4*)(ln + 4);
        }

        // center window: only q2,q3,q4 (dwords W[8..19]) needed for m=7..13
        const uint4* basep = (const uint4*)smem + c * WPC + L;
        uint4 q2 = basep[2], q3 = basep[3], q4 = basep[4];
        unsigned W[28];
        W[8]=q2.x;  W[9]=q2.y;  W[10]=q2.z; W[11]=q2.w;
        W[12]=q3.x; W[13]=q3.y; W[14]=q3.z; W[15]=q3.w;
        W[16]=q4.x; W[17]=q4.y; W[18]=q4.z; W[19]=q4.w;

        unsigned ae[4], ao[4];
#pragma unroll
        for (int r = 0; r < 4; ++r) { ae[r] = 0xFFFFFFFFu; ao[r] = 0xFFFFFFFFu; }

        // center band m=7..13 -> W[9..18] only
#pragma unroll
        for (int r = 0; r < 4; ++r)
#pragma unroll
            for (int m = 7; m <= 13; ++m) {
                ae[r] = pk_minv(ae[r], pk_add_s(W[r + m + 2], CE[m]));
                ao[r] = pk_minv(ao[r], pk_add_s(W[r + m + 2], CO[m]));
            }

        unsigned mx = pk_maxv(pk_maxv(pk_maxv(pk_hmin(ae[0]), pk_hmin(ao[0])),
                                      pk_maxv(pk_hmin(ae[1]), pk_hmin(ao[1]))),
                              pk_maxv(pk_maxv(pk_hmin(ae[2]), pk_hmin(ao[2])),
                                      pk_maxv(pk_hmin(ae[3]), pk_hmin(ao[3]))));
        if (!__all(mx <= (49u | (49u << 16)))) {
            // outer bands need W[2..11] and W[16..25]: load q0,q1,q5,q6 now
            uint4 q0 = basep[0], q1 = basep[1], q5 = basep[5], q6 = basep[6];
            W[0]=q0.x;  W[1]=q0.y;  W[2]=q0.z;  W[3]=q0.w;
            W[4]=q1.x;  W[5]=q1.y;  W[6]=q1.z;  W[7]=q1.w;
            W[20]=q5.x; W[21]=q5.y; W[22]=q5.z; W[23]=q5.w;
            W[24]=q6.x; W[25]=q6.y; W[26]=q6.z; W[27]=q6.w;
#pragma unroll
            for (int r = 0; r < 4; ++r) {
#pragma unroll
                for (int m = 0; m <= 6; ++m) {
                    ae[r] = pk_minv(ae[r], pk_add_s(W[r + m + 2], CE[m]));
                    ao[r] = pk_minv(ao[r], pk_add_s(W[r + m + 2], CO[m]));
                }
#pragma unroll
                for (int m = 14; m <= 20; ++m) {
                    ae[r] = pk_minv(ae[r], pk_add_s(W[r + m + 2], CE[m]));
                    ao[r] = pk_minv(ao[r], pk_add_s(W[r + m + 2], CO[m]));
                }
            }
        }

        float fx[8] = {f0.x, f0.y, f0.z, f0.w, f1.x, f1.y, f1.z, f1.w};
#pragma unroll
        for (int r = 0; r < 4; ++r) {
            unsigned nd0 = pk_hmin(ae[r]) & 0xFFFFu;   // px 8L+2r
            unsigned nd1 = pk_hmin(ao[r]) & 0xFFFFu;   // px 8L+2r+1
            float e0 = __expf(fx[2 * r]), e1 = __expf(fx[2 * r + 1]);
            den[2 * r] += e0; den[2 * r + 1] += e1;
            float s0 = fsqrt_fast((float)umin32(nd0, CAP2));
            float s1 = fsqrt_fast((float)umin32(nd1, CAP2));
            num[2 * r]     += e0 * s0;     // target term: e*sqrt(0)=0, self-excluded
            num[2 * r + 1] += e1 * s1;
            bool z0 = (nd0 == 0), z1 = (nd1 == 0);
            et[2 * r]     = z0 ? e0 : et[2 * r];
            et[2 * r + 1] = z1 ? e1 : et[2 * r + 1];
            m2[2 * r]     = umin32(m2[2 * r],     z0 ? 0xFFFFu : nd0);
            m2[2 * r + 1] = umin32(m2[2 * r + 1], z1 ? 0xFFFFu : nd1);
        }
    }

    // ---- two-pass merge, OVERLAID on the stage buffer ----
    __syncthreads();   // all waves done reading stage LDS; safe to overwrite
    float vsum = 0.f;
#pragma unroll
    for (int pass = 0; pass < 2; ++pass) {
        if ((L >> 5) == pass) {                 // lanes owning this half-row
            int base = 8 * (L & 31);
            *(float4*)&sNum[wid][base]     = (float4){num[0], num[1], num[2], num[3]};
            *(float4*)&sNum[wid][base + 4] = (float4){num[4], num[5], num[6], num[7]};
            *(float4*)&sDen[wid][base]     = (float4){den[0], den[1], den[2], den[3]};
            *(float4*)&sDen[wid][base + 4] = (float4){den[4], den[5], den[6], den[7]};
            *(float4*)&sEt[wid][base]      = (float4){et[0], et[1], et[2], et[3]};
            *(float4*)&sEt[wid][base + 4]  = (float4){et[4], et[5], et[6], et[7]};
            uint4 mq;
            mq.x = m2[0] | (m2[1] << 16); mq.y = m2[2] | (m2[3] << 16);
            mq.z = m2[4] | (m2[5] << 16); mq.w = m2[6] | (m2[7] << 16);
            *(uint4*)&sM2[wid][base] = mq;
        }
        __syncthreads();
        {
            float N = sNum[0][tid] + sNum[1][tid] + sNum[2][tid] + sNum[3][tid];
            float D = sDen[0][tid] + sDen[1][tid] + sDen[2][tid] + sDen[3][tid];
            float E = sEt[0][tid] + sEt[1][tid] + sEt[2][tid] + sEt[3][tid];
            unsigned M = umin32(umin32((unsigned)sM2[0][tid], (unsigned)sM2[1][tid]),
                                umin32((unsigned)sM2[2][tid], (unsigned)sM2[3][tid]));
            vsum += (N - E * fsqrt_fast((float)umin32(M, CAP2))) / D;
        }
        __syncthreads();                        // before next pass overwrites
    }

#pragma unroll
    for (int off = 32; off >= 1; off >>= 1) vsum += __shfl_down(vsum, off);
    if (L == 0) wsum[wid] = vsum;
    __syncthreads();
    if (tid == 0) {
        float s = (wsum[0] + wsum[1]) + (wsum[2] + wsum[3]);
        // fixed-point 2^36 with /20 folded in; integer atomic => deterministic
        double q = (double)s * (68719476736.0 / 20.0);
        atomicAdd(&acc[bh & 63], (unsigned long long)(long long)q);
    }
}

// one wave: parallel cell loads + shuffle reduce (integer = deterministic)
__global__ void kC_final(const unsigned long long* __restrict__ acc,
                         float* __restrict__ out) {
    int L = threadIdx.x;
    long long v = (long long)acc[L];
#pragma unroll
    for (int off = 32; off >= 1; off >>= 1) v += __shfl_down(v, off);
    if (L == 0) {
        double d = (double)v / 68719476736.0;
        out[0] = (float)(d / (double)((size_t)BB * HH * WW));
    }
}

extern "C" void kernel_launch(void* const* d_in, const int* in_sizes, int n_in,
                              void* d_out, int out_size, void* d_ws, size_t ws_size,
                              hipStream_t stream) {
    const float* logits = (const float*)d_in[0];
    const int* targ = (const int*)d_in[1];
    unsigned char* wsb = (unsigned char*)d_ws;
    unsigned long long* acc = (unsigned long long*)wsb;       // [0,512): 64 cells
    unsigned char* vneg = wsb + 1024;                         // 19.9 MB u8

    kA_vert<<<1024, 256, 0, stream>>>(targ, vneg, acc);       // 262144 threads
    kB_main<<<BB * HH, 256, 0, stream>>>(logits, vneg, acc);
    kC_final<<<1, 64, 0, stream>>>(acc, (float*)d_out);
}